// Round 3
// baseline (643.816 us; speedup 1.0000x reference)
//
#include <hip/hip_runtime.h>
#include <hip/hip_bf16.h>

// LoRALinear: out = x @ (W + 2.0*B@A)^T + bias ; M=16384, N=4096, K=4096, R=16.
// Round 3: 256x256 8-phase GEMM, MFMA switched to 32x32x16 (2495 TF ceiling vs
// 2075), redundant phase-END barriers dropped (region-race-analyzed), T2 XOR
// swizzle + counted vmcnt + setprio kept. Preps unchanged.
// ws layout: [0,134217728) x_bf16 ; [134217728, +33554432) W_eff_bf16.

typedef __attribute__((ext_vector_type(8))) short bf16x8;
typedef __attribute__((ext_vector_type(16))) float f32x16;
typedef __attribute__((ext_vector_type(4))) unsigned short u16x4;

#define M_DIM 16384
#define N_DIM 4096
#define K_DIM 4096
#define NT (K_DIM / 64)   // 64 K-tiles of BK=64

__device__ __forceinline__ unsigned short f2bf(float f) {
    unsigned int u = __builtin_bit_cast(unsigned int, f);
    unsigned int r = u + 0x7FFFu + ((u >> 16) & 1u);
    return (unsigned short)(r >> 16);
}

__device__ __forceinline__ void async16(const void* g, void* l) {
    __builtin_amdgcn_global_load_lds(
        (const __attribute__((address_space(1))) unsigned int*)g,
        (__attribute__((address_space(3))) unsigned int*)l,
        16, 0, 0);
}

// ---------------- prep kernel 1: x fp32 -> bf16 ----------------
__global__ void __launch_bounds__(256) cast_x_kernel(
    const float4* __restrict__ x, u16x4* __restrict__ y, int n4) {
    int i = blockIdx.x * blockDim.x + threadIdx.x;
    int stride = gridDim.x * blockDim.x;
    for (; i < n4; i += stride) {
        float4 v = x[i];
        u16x4 o = { f2bf(v.x), f2bf(v.y), f2bf(v.z), f2bf(v.w) };
        y[i] = o;
    }
}

// ---------------- prep kernel 2: W_eff = W + 2*B@A -> bf16 ----------------
__global__ void __launch_bounds__(256) weff_kernel(
    const float* __restrict__ W, const float* __restrict__ lA,
    const float* __restrict__ lB, unsigned short* __restrict__ out) {
    constexpr int K = K_DIM, R = 16;
    constexpr float S = 2.0f;  // 32.0 / 16
    int o = blockIdx.x;
    int t = threadIdx.x;
    float b[R];
#pragma unroll
    for (int r = 0; r < R; ++r) b[r] = lB[o * R + r];
#pragma unroll
    for (int c = 0; c < 4; ++c) {
        int i = c * 1024 + t * 4;
        float4 wv = *reinterpret_cast<const float4*>(&W[o * K + i]);
        float sx = 0.f, sy = 0.f, sz = 0.f, sw = 0.f;
#pragma unroll
        for (int r = 0; r < R; ++r) {
            float4 a = *reinterpret_cast<const float4*>(&lA[r * K + i]);
            sx += b[r] * a.x; sy += b[r] * a.y;
            sz += b[r] * a.z; sw += b[r] * a.w;
        }
        u16x4 ov = { f2bf(wv.x + S * sx), f2bf(wv.y + S * sy),
                     f2bf(wv.z + S * sz), f2bf(wv.w + S * sw) };
        *reinterpret_cast<u16x4*>(&out[o * K + i]) = ov;
    }
}

// ---------------- main GEMM: 256x256 tile, 8-wave, 32x32x16 MFMA ----------------
// LDS buffer (x2 dbuf): A tile 256x64 bf16 [0,32768) + B tile [32768,65536),
// 128B rows, XOR-swizzled: phys = row*128 + (colbyte ^ ((row&7)<<4)).
// Stage linear via global_load_lds with lane-pre-swizzled global source.
#define STAGE(G, h, tt, bsel, moff)                                           \
    do {                                                                      \
        const unsigned short* g0 = (G) +                                      \
            (size_t)((h) * 128 + wid * 16 + rc) * K_DIM + (tt) * 64 + cc * 8; \
        char* l0 = lds + (bsel) * 65536 + (moff) + (h) * 16384 + wid * 2048;  \
        async16(g0, l0);                                                      \
        async16(g0 + 8 * K_DIM, l0 + 1024);                                   \
    } while (0)

// A frag (m, ks): lane -> row = wm*128 + m*32 + (l&31), k-bytes = kx[ks]
#define LDA32(mh, bsel)                                                       \
    _Pragma("unroll") for (int mm = 0; mm < 2; ++mm)                          \
    _Pragma("unroll") for (int ks = 0; ks < 4; ++ks)                          \
        ar[mm][ks] = *(const bf16x8*)(lds + (bsel) * 65536 + aoff +           \
            ((mh) * 2 + mm) * 4096 + kx[ks]);

#define LDB32(nh, bsel)                                                       \
    _Pragma("unroll") for (int ks = 0; ks < 4; ++ks)                          \
        br[nh][ks] = *(const bf16x8*)(lds + (bsel) * 65536 + boff +           \
            (nh) * 4096 + kx[ks]);

// ks outer, mm inner: 2 independent acc chains interleaved
#define MM32(mh, nh)                                                          \
    _Pragma("unroll") for (int ks = 0; ks < 4; ++ks)                          \
    _Pragma("unroll") for (int mm = 0; mm < 2; ++mm)                          \
        acc[(mh) * 2 + mm][nh] = __builtin_amdgcn_mfma_f32_32x32x16_bf16(     \
            ar[mm][ks], br[nh][ks], acc[(mh) * 2 + mm][nh], 0, 0, 0);

#define PHASE_MID()                                                           \
    __builtin_amdgcn_s_barrier();                                             \
    asm volatile("s_waitcnt lgkmcnt(0)" ::: "memory");                        \
    __builtin_amdgcn_s_setprio(1)

__global__ void __launch_bounds__(512, 2) gemm8p_kernel(
    const unsigned short* __restrict__ A,
    const unsigned short* __restrict__ B,
    const float* __restrict__ bias,
    float* __restrict__ C) {
    __shared__ __align__(1024) char lds[131072];

    const int tid = threadIdx.x;
    const int lane = tid & 63, wid = tid >> 6;
    const int wm = wid >> 2, wn = wid & 3;   // 2 x 4 waves
    const int lc = lane & 31, hi = lane >> 5;

    // XCD-aware swizzle: 1024 blocks (divisible by 8)
    const int bid = blockIdx.x;
    const int swz = (bid & 7) * 128 + (bid >> 3);
    const int bm = swz >> 4, bn = swz & 15;  // 64 x 16 tiles

    const unsigned short* Ag = A + (size_t)bm * 256 * K_DIM;
    const unsigned short* Bg = B + (size_t)bn * 256 * K_DIM;

    // staging lane pre-swizzle (inverse of the read XOR)
    const int lam = lane ^ (lane >> 3);
    const int rc = lam >> 3, cc = lam & 7;

    // read-side swizzled k-slot bytes: ((ks<<5)|hb) ^ sw, sw/hb disjoint-safe
    const int sw = (lane & 7) << 4;
    int kx[4];
#pragma unroll
    for (int ks = 0; ks < 4; ++ks) kx[ks] = ((ks << 5) | (hi << 4)) ^ sw;
    const int aoff = (wm * 128 + lc) * 128;           // A region row base
    const int boff = 32768 + (wn * 64 + lc) * 128;    // B region row base

    f32x16 acc[4][2] = {};
    bf16x8 ar[2][4], br[2][4];

    // prologue: t0.B0, t0.B1, t0.A0, t0.A1, t1.B0, t1.B1
    STAGE(Bg, 0, 0, 0, 32768);
    STAGE(Bg, 1, 0, 0, 32768);
    STAGE(Ag, 0, 0, 0, 0);
    STAGE(Ag, 1, 0, 0, 0);
    STAGE(Bg, 0, 1, 1, 32768);
    STAGE(Bg, 1, 1, 1, 32768);
    asm volatile("s_waitcnt vmcnt(4)" ::: "memory");
    __builtin_amdgcn_s_barrier();

#pragma unroll 2
    for (int t = 0; t < NT; ++t) {
        const int bs = t & 1, bo = bs ^ 1;
        // ---- phase 0: (mh=0, nh=0). END-0 dropped: phase-1 STAGE targets
        // the other buffer -> no region overlap with phase-0 reads.
        LDA32(0, bs);
        LDB32(0, bs);
        if (t + 1 < NT) STAGE(Ag, 0, t + 1, bo, 0);
        PHASE_MID();
        MM32(0, 0);
        __builtin_amdgcn_s_setprio(0);
        // ---- phase 1: (0,1). END-1 REQUIRED: phase-2 STAGE overwrites
        // bs.B[0:128) which phase-1 LDB reads for wn in {0,1}.
        LDB32(1, bs);
        if (t + 1 < NT) STAGE(Ag, 1, t + 1, bo, 0);
        PHASE_MID();
        MM32(0, 1);
        __builtin_amdgcn_s_setprio(0);
        __builtin_amdgcn_s_barrier();
        // ---- phase 2: (1,0). END-2 dropped: phase-3 STAGE targets B region,
        // phase-2 reads only A; phase-1 B reads completed before MID-2.
        LDA32(1, bs);
        if (t + 2 < NT) STAGE(Bg, 0, t + 2, bs, 32768);
        PHASE_MID();
        MM32(1, 0);
        __builtin_amdgcn_s_setprio(0);
        // ---- phase 3: (1,1) + K-tile boundary counted vmcnt
        if (t + 2 < NT) STAGE(Bg, 1, t + 2, bs, 32768);
        PHASE_MID();
        MM32(1, 1);
        __builtin_amdgcn_s_setprio(0);
        if (t + 2 < NT) {
            asm volatile("s_waitcnt vmcnt(4)" ::: "memory");
        } else {
            asm volatile("s_waitcnt vmcnt(0)" ::: "memory");
        }
        __builtin_amdgcn_s_barrier();
    }

    // epilogue: 32x32 D layout: col = lane&31, row = (reg&3)+8*(reg>>2)+4*hi
    const int row0 = bm * 256 + wm * 128;
    const int col0 = bn * 256 + wn * 64;
#pragma unroll
    for (int n = 0; n < 2; ++n) {
        const int col = col0 + n * 32 + lc;
        const float bv = bias[col];
#pragma unroll
        for (int m = 0; m < 4; ++m) {
#pragma unroll
            for (int g = 0; g < 4; ++g) {
#pragma unroll
                for (int r = 0; r < 4; ++r) {
                    const int row = row0 + m * 32 + g * 8 + 4 * hi + r;
                    C[(size_t)row * N_DIM + col] = acc[m][n][g * 4 + r] + bv;
                }
            }
        }
    }
}

extern "C" void kernel_launch(void* const* d_in, const int* in_sizes, int n_in,
                              void* d_out, int out_size, void* d_ws, size_t ws_size,
                              hipStream_t stream) {
    const float* x    = (const float*)d_in[0];  // [4,4096,4096]
    const float* W    = (const float*)d_in[1];  // [4096,4096]
    const float* bias = (const float*)d_in[2];  // [4096]
    const float* lA   = (const float*)d_in[3];  // [16,4096]
    const float* lB   = (const float*)d_in[4];  // [4096,16]
    float* out = (float*)d_out;

    unsigned short* xb   = (unsigned short*)d_ws;                       // 134 MB
    unsigned short* weff = (unsigned short*)((char*)d_ws + 134217728);  // 32 MB

    cast_x_kernel<<<2048, 256, 0, stream>>>((const float4*)x, (u16x4*)xb,
                                            M_DIM * K_DIM / 4);
    weff_kernel<<<N_DIM, 256, 0, stream>>>(W, lA, lB, weff);
    gemm8p_kernel<<<(M_DIM / 256) * (N_DIM / 256), 512, 0, stream>>>(
        xb, weff, bias, out);
}